// Round 16
// baseline (88.792 us; speedup 1.0000x reference)
//
#include <hip/hip_runtime.h>
#include <hip/hip_bf16.h>

// Problem constants
#define B_ 2
#define N_ 48
#define H_ 256
#define NH_ 8
#define DH_ 32
#define SQS_LD 68  // sqS row stride (floats); 272B, 16B-aligned
#define SVT_LD 52  // svT row stride (floats); 208B, 16B-aligned; 48 j + 4 pad

typedef __attribute__((ext_vector_type(8))) short bf16x8;
typedef __attribute__((ext_vector_type(4))) float f32x4;

__device__ __forceinline__ unsigned short f2bf(float f) {
  unsigned u = __float_as_uint(f);
  u += 0x7FFFu + ((u >> 16) & 1u);
  return (unsigned short)(u >> 16);
}

// pack 8 floats -> 8 bf16 (RNE) via v_cvt_pk_bf16_f32
__device__ __forceinline__ bf16x8 cvt8(f32x4 x, f32x4 y) {
  union { unsigned u[4]; bf16x8 v; } o;
  asm("v_cvt_pk_bf16_f32 %0, %1, %2" : "=v"(o.u[0]) : "v"(x.x), "v"(x.y));
  asm("v_cvt_pk_bf16_f32 %0, %1, %2" : "=v"(o.u[1]) : "v"(x.z), "v"(x.w));
  asm("v_cvt_pk_bf16_f32 %0, %1, %2" : "=v"(o.u[2]) : "v"(y.x), "v"(y.y));
  asm("v_cvt_pk_bf16_f32 %0, %1, %2" : "=v"(o.u[3]) : "v"(y.z), "v"(y.w));
  return o.v;
}

// Raw barrier WITHOUT vmcnt drain (keeps global loads in flight across it)
__device__ __forceinline__ void bar_lgkm() {
  asm volatile("s_waitcnt lgkmcnt(0)" ::: "memory");
  __builtin_amdgcn_s_barrier();
  asm volatile("" ::: "memory");
}

// ---------------------------------------------------------------------------
// Stage a 48x256 f32 tile -> bf16 LDS.  byte = row*512 + col*2, XOR
// ^((row&7)<<4) both sides.
// ---------------------------------------------------------------------------
__device__ __forceinline__ void stage48x256(const float* __restrict__ src, char* tAc, int tid) {
#pragma unroll
  for (int it = 0; it < 4; ++it) {
    int c = it * 384 + tid;
    const f32x4* g = reinterpret_cast<const f32x4*>(src) + (c << 1);
    f32x4 x = g[0];
    f32x4 y = g[1];
    int row = c >> 5;
    int off = (row << 9) + ((c & 31) << 4);
    off ^= (row & 7) << 4;
    *reinterpret_cast<bf16x8*>(tAc + off) = cvt8(x, y);
  }
}

// ---------------------------------------------------------------------------
// Pair projections (self-packing; no pack_kernel).
// Output: ONE bf16 plane pqkv [4608][768] (q|k|v).  gn==7 blocks also
// side-pack wfrag_main + biasm for e2e.
// ---------------------------------------------------------------------------
__global__ __launch_bounds__(384, 3)
void pair_proj_kernel(const float* __restrict__ pair,
                      const float* __restrict__ Wq, const float* __restrict__ Wk,
                      const float* __restrict__ Wv, const float* __restrict__ bq,
                      const float* __restrict__ bk, const float* __restrict__ bv,
                      const float* __restrict__ Wsq, const float* __restrict__ Wsk,
                      const float* __restrict__ Wsv, const float* __restrict__ bsq,
                      const float* __restrict__ bsk, const float* __restrict__ bsv,
                      unsigned short* __restrict__ pqkv,
                      unsigned short* __restrict__ wfrag_main, float* __restrict__ biasm) {
  __shared__ __align__(16) char tAc[48 * 256 * 2];
  int tid = threadIdx.x;
  int lane = tid & 63;
  int wave = tid >> 6;
  int gm = blockIdx.x >> 3;  // (b,i) group
  int gn = blockIdx.x & 7;   // 96-col group

  stage48x256(pair + (size_t)gm * 12288, tAc, tid);

  int col = gn * 96 + wave * 16 + (lane & 15);
  const float* Wsel = (col < 256) ? Wq : (col < 512) ? Wk : Wv;
  const float* bsel = (col < 256) ? bq : (col < 512) ? bk : bv;
  int cc = col & 255;
  bf16x8 wf[8];
#pragma unroll
  for (int kt = 0; kt < 8; ++kt) {
    int kbase = kt * 32 + ((lane >> 4) << 3);
    f32x4 w0, w1;
    w0.x = Wsel[(kbase + 0) * 256 + cc];
    w0.y = Wsel[(kbase + 1) * 256 + cc];
    w0.z = Wsel[(kbase + 2) * 256 + cc];
    w0.w = Wsel[(kbase + 3) * 256 + cc];
    w1.x = Wsel[(kbase + 4) * 256 + cc];
    w1.y = Wsel[(kbase + 5) * 256 + cc];
    w1.z = Wsel[(kbase + 6) * 256 + cc];
    w1.w = Wsel[(kbase + 7) * 256 + cc];
    wf[kt] = cvt8(w0, w1);
  }
  float bias = bsel[cc];

  if (gn == 7) {
    if (tid < 256) {
      int p = gm * 256 + tid;
      int i8 = p & 7, l2 = (p >> 3) & 63, kt2 = (p >> 9) & 7, nt2 = p >> 12;
      int k2 = kt2 * 32 + ((l2 >> 4) << 3) + i8;
      int n2 = nt2 * 16 + (l2 & 15);
      const float* W = (n2 < 32) ? Wsq : (n2 < 64) ? Wsk : Wsv;
      wfrag_main[p] = f2bf(W[k2 * 32 + (n2 & 31)]);
    } else if (gm == 0 && tid < 352) {
      int p = tid - 256;
      biasm[p] = (p < 32) ? bsq[p] : (p < 64) ? bsk[p - 32] : bsv[p - 64];
    }
  }
  __syncthreads();

  f32x4 acc[3];
#pragma unroll
  for (int mt = 0; mt < 3; ++mt) acc[mt] = (f32x4){0.f, 0.f, 0.f, 0.f};
#pragma unroll
  for (int kt = 0; kt < 8; ++kt) {
#pragma unroll
    for (int mt = 0; mt < 3; ++mt) {
      int row = mt * 16 + (lane & 15);
      int off = (row << 9) + (kt << 6) + ((lane >> 4) << 4);
      off ^= (row & 7) << 4;
      bf16x8 a = *reinterpret_cast<const bf16x8*>(tAc + off);
      acc[mt] = __builtin_amdgcn_mfma_f32_16x16x32_bf16(a, wf[kt], acc[mt], 0, 0, 0);
    }
  }

  int jb = (lane >> 4) * 4;
#pragma unroll
  for (int mt = 0; mt < 3; ++mt) {
#pragma unroll
    for (int rr = 0; rr < 4; ++rr) {
      int j = mt * 16 + jb + rr;
      pqkv[(size_t)(gm * 48 + j) * 768 + col] = f2bf(acc[mt][rr] + bias);
    }
  }
}

// ---------------------------------------------------------------------------
// Fused main (R14 + nontemporal trip loads / out stores).
// trip is read-once (226 MB stream): nt loads keep it from evicting pqkv
// (0.9 MB/XCD working set) out of L2, so scores/PV q/v reads stay L2-hot.
// ---------------------------------------------------------------------------
__global__ __launch_bounds__(384, 6)
void e2e_fused(const float* __restrict__ mask, const float* __restrict__ trip,
               const unsigned short* __restrict__ pqkv,
               const unsigned short* __restrict__ wfragm,
               const float* __restrict__ biasm, float* __restrict__ out) {
  __shared__ __align__(16) char smem[48 * 256 * 2];  // tAc, later sqS[48][68]
  __shared__ __align__(16) float svT[32 * SVT_LD];   // 6656 B, d-major
  __shared__ __align__(16) float khl[256];
  __shared__ __align__(16) float pbuf[8][48];
  char* tAc = smem;
  float* sqS = reinterpret_cast<float*>(smem);  // [48][SQS_LD] = 13056 B

  int tid = threadIdx.x;
  int lane = tid & 63;
  int wave = tid >> 6;

  int bid = blockIdx.x;
  int s = (bid & 7) * 576 + (bid >> 3);  // slice = (b*48+i)*48 + k
  int g = s / 48;
  int k = s % 48;
  int b = g / 48;
  int rowbase = g * 48;

  // mask for this thread's scores role (j = tid>>3), prefetched to reg
  float maskr = mask[b * 2304 + k * 48 + (tid >> 3)];

  // k-row (bf16 -> f32 LDS)
  if (tid < 256) {
    unsigned short kv = pqkv[(size_t)s * 768 + 256 + tid];
    khl[tid] = __uint_as_float((unsigned)kv << 16);
  }

  // K-split staged load (nontemporal: trip is a read-once stream).
  const f32x4* src = reinterpret_cast<const f32x4*>(trip + (size_t)s * 12288);
  int r0 = tid >> 4, c0 = tid & 15;
  int r1 = (384 + tid) >> 4, c1 = tid & 15;
  f32x4 pa[4], pb[4];
  pa[0] = __builtin_nontemporal_load(src + r0 * 64 + c0 * 2);
  pa[1] = __builtin_nontemporal_load(src + r0 * 64 + c0 * 2 + 1);
  pa[2] = __builtin_nontemporal_load(src + r1 * 64 + c1 * 2);
  pa[3] = __builtin_nontemporal_load(src + r1 * 64 + c1 * 2 + 1);
  pb[0] = __builtin_nontemporal_load(src + r0 * 64 + 32 + c0 * 2);
  pb[1] = __builtin_nontemporal_load(src + r0 * 64 + 32 + c0 * 2 + 1);
  pb[2] = __builtin_nontemporal_load(src + r1 * 64 + 32 + c1 * 2);
  pb[3] = __builtin_nontemporal_load(src + r1 * 64 + 32 + c1 * 2 + 1);

  {  // write half1 (waits only on pa's loads via in-order vmcnt)
    int off0 = (r0 << 9) + (c0 << 4);
    off0 ^= (r0 & 7) << 4;
    *reinterpret_cast<bf16x8*>(tAc + off0) = cvt8(pa[0], pa[1]);
    int off1 = (r1 << 9) + (c1 << 4);
    off1 ^= (r1 & 7) << 4;
    *reinterpret_cast<bf16x8*>(tAc + off1) = cvt8(pa[2], pa[3]);
  }
  bar_lgkm();  // [1] half1 staged; pb loads still in flight

  // GEMM kt0-3; B-frags from L2 per kt
  const bf16x8* wp = reinterpret_cast<const bf16x8*>(wfragm);
  f32x4 acc[3];
#pragma unroll
  for (int mt = 0; mt < 3; ++mt) acc[mt] = (f32x4){0.f, 0.f, 0.f, 0.f};
#pragma unroll
  for (int kt = 0; kt < 4; ++kt) {
    bf16x8 w = wp[(wave * 8 + kt) * 64 + lane];
#pragma unroll
    for (int mt = 0; mt < 3; ++mt) {
      int row = mt * 16 + (lane & 15);
      int off = (row << 9) + (kt << 6) + ((lane >> 4) << 4);
      off ^= (row & 7) << 4;
      bf16x8 a = *reinterpret_cast<const bf16x8*>(tAc + off);
      acc[mt] = __builtin_amdgcn_mfma_f32_16x16x32_bf16(a, w, acc[mt], 0, 0, 0);
    }
  }
  {  // write half2
    int off0 = (r0 << 9) + ((16 + c0) << 4);
    off0 ^= (r0 & 7) << 4;
    *reinterpret_cast<bf16x8*>(tAc + off0) = cvt8(pb[0], pb[1]);
    int off1 = (r1 << 9) + ((16 + c1) << 4);
    off1 ^= (r1 & 7) << 4;
    *reinterpret_cast<bf16x8*>(tAc + off1) = cvt8(pb[2], pb[3]);
  }
  bar_lgkm();  // [2] half2 staged

#pragma unroll
  for (int kt = 4; kt < 8; ++kt) {
    bf16x8 w = wp[(wave * 8 + kt) * 64 + lane];
#pragma unroll
    for (int mt = 0; mt < 3; ++mt) {
      int row = mt * 16 + (lane & 15);
      int off = (row << 9) + (kt << 6) + ((lane >> 4) << 4);
      off ^= (row & 7) << 4;
      bf16x8 a = *reinterpret_cast<const bf16x8*>(tAc + off);
      acc[mt] = __builtin_amdgcn_mfma_f32_16x16x32_bf16(a, w, acc[mt], 0, 0, 0);
    }
  }
  bar_lgkm();  // [3] tAc reads done; smem becomes sqS

  // epilogue: waves 0-3 -> sqS[j][n] (sq|sk); waves 4-5 -> svT[d][j] (sv)
  {
    int n = wave * 16 + (lane & 15);
    float bias = biasm[n];
    int jb = (lane >> 4) * 4;
    if (wave < 4) {
#pragma unroll
      for (int mt = 0; mt < 3; ++mt) {
#pragma unroll
        for (int rr = 0; rr < 4; ++rr)
          sqS[(mt * 16 + jb + rr) * SQS_LD + n] = acc[mt][rr] + bias;
      }
    } else {
      int d = n - 64;
#pragma unroll
      for (int mt = 0; mt < 3; ++mt) {
#pragma unroll
        for (int rr = 0; rr < 4; ++rr)
          svT[d * SVT_LD + mt * 16 + jb + rr] = acc[mt][rr] + bias;
      }
    }
  }
  bar_lgkm();  // [4] sqS/svT ready

  // scores: thread (j = tid>>3, dq = tid&7); sq/sk read ONCE, 8 h partials,
  // 3-step shfl_xor reduce within the 8-thread dq group.
  {
    int j = tid >> 3, dq = tid & 7;
    f32x4 sq = *reinterpret_cast<const f32x4*>(sqS + j * SQS_LD + dq * 4);
    f32x4 sk = *reinterpret_cast<const f32x4*>(sqS + j * SQS_LD + 32 + dq * 4);
    const unsigned short* qrow = pqkv + (size_t)(rowbase + j) * 768;
    float val[8];
#pragma unroll
    for (int h = 0; h < 8; ++h) {
      uint2 qw = *reinterpret_cast<const uint2*>(qrow + h * 32 + dq * 4);
      f32x4 kh = *reinterpret_cast<const f32x4*>(khl + h * 32 + dq * 4);
      float v = (__uint_as_float(qw.x << 16) + sq.x) * (kh.x + sk.x);
      v += (__uint_as_float(qw.x & 0xFFFF0000u) + sq.y) * (kh.y + sk.y);
      v += (__uint_as_float(qw.y << 16) + sq.z) * (kh.z + sk.z);
      v += (__uint_as_float(qw.y & 0xFFFF0000u) + sq.w) * (kh.w + sk.w);
      val[h] = v;
    }
#pragma unroll
    for (int h = 0; h < 8; ++h) {
      val[h] += __shfl_xor(val[h], 1);
      val[h] += __shfl_xor(val[h], 2);
      val[h] += __shfl_xor(val[h], 4);
    }
    float sc = val[0];
#pragma unroll
    for (int h = 1; h < 8; ++h) sc = (dq == h) ? val[h] : sc;  // static select
    pbuf[dq][j] = sc * 0.17677669529663687f + maskr;
  }
  bar_lgkm();  // [5] scores ready

  // softmax: wave w (<4) handles heads {2w, 2w+1} == the heads its own PV
  // threads read -> no barrier needed between softmax and PV (wave-coherent
  // LDS; lgkmcnt(0) below orders the ds_write -> ds_read within the wave).
  if (wave < 4) {
#pragma unroll
    for (int hh = 0; hh < 2; ++hh) {
      int h = wave * 2 + hh;
      float x = (lane < 48) ? pbuf[h][lane] : -INFINITY;
      float m = x;
#pragma unroll
      for (int off = 32; off; off >>= 1) m = fmaxf(m, __shfl_xor(m, off));
      float e = (lane < 48) ? __expf(x - m) : 0.f;
      float sum = e;
#pragma unroll
      for (int off = 32; off; off >>= 1) sum += __shfl_xor(sum, off);
      if (lane < 48) pbuf[h][lane] = e / sum;
    }
    asm volatile("s_waitcnt lgkmcnt(0)" ::: "memory");

    // PV: thread (h = tid>>5, d = tid&31); v bf16 from pqkv (L2), sv/p LDS
    int h = tid >> 5, d = tid & 31;
    const unsigned short* vbase = pqkv + (size_t)rowbase * 768 + 512 + tid % 256;
    float a = 0.f;
#pragma unroll
    for (int j4 = 0; j4 < 12; ++j4) {
      f32x4 p4 = *reinterpret_cast<const f32x4*>(&pbuf[h][j4 * 4]);
      f32x4 sv4 = *reinterpret_cast<const f32x4*>(svT + d * SVT_LD + j4 * 4);
      float v0 = __uint_as_float((unsigned)vbase[(size_t)(j4 * 4 + 0) * 768] << 16);
      float v1 = __uint_as_float((unsigned)vbase[(size_t)(j4 * 4 + 1) * 768] << 16);
      float v2 = __uint_as_float((unsigned)vbase[(size_t)(j4 * 4 + 2) * 768] << 16);
      float v3 = __uint_as_float((unsigned)vbase[(size_t)(j4 * 4 + 3) * 768] << 16);
      a += p4.x * (v0 + sv4.x);
      a += p4.y * (v1 + sv4.y);
      a += p4.z * (v2 + sv4.z);
      a += p4.w * (v3 + sv4.w);
    }
    __builtin_nontemporal_store(a, out + (size_t)s * 256 + tid);
  }
}

// ---------------------------------------------------------------------------
extern "C" void kernel_launch(void* const* d_in, const int* in_sizes, int n_in,
                              void* d_out, int out_size, void* d_ws, size_t ws_size,
                              hipStream_t stream) {
  const float* mask = (const float*)d_in[0];
  const float* pair = (const float*)d_in[1];
  const float* trip = (const float*)d_in[2];
  const float* Wq = (const float*)d_in[3];
  const float* bq = (const float*)d_in[4];
  const float* Wk = (const float*)d_in[5];
  const float* bk = (const float*)d_in[6];
  const float* Wv = (const float*)d_in[7];
  const float* bv = (const float*)d_in[8];
  const float* Wsq = (const float*)d_in[9];
  const float* bsq = (const float*)d_in[10];
  const float* Wsk = (const float*)d_in[11];
  const float* bsk = (const float*)d_in[12];
  const float* Wsv = (const float*)d_in[13];
  const float* bsv = (const float*)d_in[14];

  char* ws = (char*)d_ws;
  unsigned short* pqkv = (unsigned short*)ws;                    // 7,077,888 B
  unsigned short* wfrag_main = (unsigned short*)(ws + 7077888);  // 49,152 B
  float* biasm = (float*)(ws + 7127040);                         // 384 B

  pair_proj_kernel<<<768, 384, 0, stream>>>(pair, Wq, Wk, Wv, bq, bk, bv,
                                            Wsq, Wsk, Wsv, bsq, bsk, bsv,
                                            pqkv, wfrag_main, biasm);
  e2e_fused<<<4608, 384, 0, stream>>>(mask, trip, pqkv, wfrag_main, biasm,
                                      (float*)d_out);
}

// Round 17
// 70.300 us; speedup vs baseline: 1.2630x; 1.2630x over previous
//
#include <hip/hip_runtime.h>
#include <hip/hip_bf16.h>

// Problem constants
#define B_ 2
#define N_ 48
#define H_ 256
#define NH_ 8
#define DH_ 32
#define SQS_LD 68  // sqS row stride (floats); 272B, 16B-aligned
#define SVT_LD 52  // svT row stride (floats); 208B, 16B-aligned; 48 j + 4 pad

typedef __attribute__((ext_vector_type(8))) short bf16x8;
typedef __attribute__((ext_vector_type(4))) float f32x4;

__device__ __forceinline__ unsigned short f2bf(float f) {
  unsigned u = __float_as_uint(f);
  u += 0x7FFFu + ((u >> 16) & 1u);
  return (unsigned short)(u >> 16);
}

// pack 8 floats -> 8 bf16 (RNE) via v_cvt_pk_bf16_f32
__device__ __forceinline__ bf16x8 cvt8(f32x4 x, f32x4 y) {
  union { unsigned u[4]; bf16x8 v; } o;
  asm("v_cvt_pk_bf16_f32 %0, %1, %2" : "=v"(o.u[0]) : "v"(x.x), "v"(x.y));
  asm("v_cvt_pk_bf16_f32 %0, %1, %2" : "=v"(o.u[1]) : "v"(x.z), "v"(x.w));
  asm("v_cvt_pk_bf16_f32 %0, %1, %2" : "=v"(o.u[2]) : "v"(y.x), "v"(y.y));
  asm("v_cvt_pk_bf16_f32 %0, %1, %2" : "=v"(o.u[3]) : "v"(y.z), "v"(y.w));
  return o.v;
}

// Raw barrier WITHOUT vmcnt drain (keeps global loads in flight across it)
__device__ __forceinline__ void bar_lgkm() {
  asm volatile("s_waitcnt lgkmcnt(0)" ::: "memory");
  __builtin_amdgcn_s_barrier();
  asm volatile("" ::: "memory");
}

// ---------------------------------------------------------------------------
// Stage a 48x256 f32 tile -> bf16 LDS.  byte = row*512 + col*2, XOR
// ^((row&7)<<4) both sides.
// ---------------------------------------------------------------------------
__device__ __forceinline__ void stage48x256(const float* __restrict__ src, char* tAc, int tid) {
#pragma unroll
  for (int it = 0; it < 4; ++it) {
    int c = it * 384 + tid;
    const f32x4* g = reinterpret_cast<const f32x4*>(src) + (c << 1);
    f32x4 x = g[0];
    f32x4 y = g[1];
    int row = c >> 5;
    int off = (row << 9) + ((c & 31) << 4);
    off ^= (row & 7) << 4;
    *reinterpret_cast<bf16x8*>(tAc + off) = cvt8(x, y);
  }
}

// ---------------------------------------------------------------------------
// Pair projections (self-packing; no pack_kernel).
// Output: ONE bf16 plane pqkv [4608][768] (q|k|v).  gn==7 blocks also
// side-pack wfrag_main + biasm for e2e.
// ---------------------------------------------------------------------------
__global__ __launch_bounds__(384, 3)
void pair_proj_kernel(const float* __restrict__ pair,
                      const float* __restrict__ Wq, const float* __restrict__ Wk,
                      const float* __restrict__ Wv, const float* __restrict__ bq,
                      const float* __restrict__ bk, const float* __restrict__ bv,
                      const float* __restrict__ Wsq, const float* __restrict__ Wsk,
                      const float* __restrict__ Wsv, const float* __restrict__ bsq,
                      const float* __restrict__ bsk, const float* __restrict__ bsv,
                      unsigned short* __restrict__ pqkv,
                      unsigned short* __restrict__ wfrag_main, float* __restrict__ biasm) {
  __shared__ __align__(16) char tAc[48 * 256 * 2];
  int tid = threadIdx.x;
  int lane = tid & 63;
  int wave = tid >> 6;
  int gm = blockIdx.x >> 3;  // (b,i) group
  int gn = blockIdx.x & 7;   // 96-col group

  stage48x256(pair + (size_t)gm * 12288, tAc, tid);

  int col = gn * 96 + wave * 16 + (lane & 15);
  const float* Wsel = (col < 256) ? Wq : (col < 512) ? Wk : Wv;
  const float* bsel = (col < 256) ? bq : (col < 512) ? bk : bv;
  int cc = col & 255;
  bf16x8 wf[8];
#pragma unroll
  for (int kt = 0; kt < 8; ++kt) {
    int kbase = kt * 32 + ((lane >> 4) << 3);
    f32x4 w0, w1;
    w0.x = Wsel[(kbase + 0) * 256 + cc];
    w0.y = Wsel[(kbase + 1) * 256 + cc];
    w0.z = Wsel[(kbase + 2) * 256 + cc];
    w0.w = Wsel[(kbase + 3) * 256 + cc];
    w1.x = Wsel[(kbase + 4) * 256 + cc];
    w1.y = Wsel[(kbase + 5) * 256 + cc];
    w1.z = Wsel[(kbase + 6) * 256 + cc];
    w1.w = Wsel[(kbase + 7) * 256 + cc];
    wf[kt] = cvt8(w0, w1);
  }
  float bias = bsel[cc];

  if (gn == 7) {
    if (tid < 256) {
      int p = gm * 256 + tid;
      int i8 = p & 7, l2 = (p >> 3) & 63, kt2 = (p >> 9) & 7, nt2 = p >> 12;
      int k2 = kt2 * 32 + ((l2 >> 4) << 3) + i8;
      int n2 = nt2 * 16 + (l2 & 15);
      const float* W = (n2 < 32) ? Wsq : (n2 < 64) ? Wsk : Wsv;
      wfrag_main[p] = f2bf(W[k2 * 32 + (n2 & 31)]);
    } else if (gm == 0 && tid < 352) {
      int p = tid - 256;
      biasm[p] = (p < 32) ? bsq[p] : (p < 64) ? bsk[p - 32] : bsv[p - 64];
    }
  }
  __syncthreads();

  f32x4 acc[3];
#pragma unroll
  for (int mt = 0; mt < 3; ++mt) acc[mt] = (f32x4){0.f, 0.f, 0.f, 0.f};
#pragma unroll
  for (int kt = 0; kt < 8; ++kt) {
#pragma unroll
    for (int mt = 0; mt < 3; ++mt) {
      int row = mt * 16 + (lane & 15);
      int off = (row << 9) + (kt << 6) + ((lane >> 4) << 4);
      off ^= (row & 7) << 4;
      bf16x8 a = *reinterpret_cast<const bf16x8*>(tAc + off);
      acc[mt] = __builtin_amdgcn_mfma_f32_16x16x32_bf16(a, wf[kt], acc[mt], 0, 0, 0);
    }
  }

  int jb = (lane >> 4) * 4;
#pragma unroll
  for (int mt = 0; mt < 3; ++mt) {
#pragma unroll
    for (int rr = 0; rr < 4; ++rr) {
      int j = mt * 16 + jb + rr;
      pqkv[(size_t)(gm * 48 + j) * 768 + col] = f2bf(acc[mt][rr] + bias);
    }
  }
}

// ---------------------------------------------------------------------------
// Fused main (R14 structure, best known: 71.2us).  One block per (b,i,k).
//  - K-split double-stage (half2 loads in flight across GEMM kt0-3)
//  - scores: (j,dq) mapping, sq/sk read ONCE per thread, shfl_xor reduce
//  - sv stored d-major (svT[32][52] f32) -> PV reads float4
//  - waves 0-3 softmax their own PV heads {2w,2w+1}: no softmax->PV barrier
//  - NO nontemporal hints: trip stays L3-resident across graph replays
//    (R16 measured +17us when nt bypassed L3 allocation)
// ---------------------------------------------------------------------------
__global__ __launch_bounds__(384, 6)
void e2e_fused(const float* __restrict__ mask, const float* __restrict__ trip,
               const unsigned short* __restrict__ pqkv,
               const unsigned short* __restrict__ wfragm,
               const float* __restrict__ biasm, float* __restrict__ out) {
  __shared__ __align__(16) char smem[48 * 256 * 2];  // tAc, later sqS[48][68]
  __shared__ __align__(16) float svT[32 * SVT_LD];   // 6656 B, d-major
  __shared__ __align__(16) float khl[256];
  __shared__ __align__(16) float pbuf[8][48];
  char* tAc = smem;
  float* sqS = reinterpret_cast<float*>(smem);  // [48][SQS_LD] = 13056 B

  int tid = threadIdx.x;
  int lane = tid & 63;
  int wave = tid >> 6;

  int bid = blockIdx.x;
  int s = (bid & 7) * 576 + (bid >> 3);  // slice = (b*48+i)*48 + k
  int g = s / 48;
  int k = s % 48;
  int b = g / 48;
  int rowbase = g * 48;

  // mask for this thread's scores role (j = tid>>3), prefetched to reg
  float maskr = mask[b * 2304 + k * 48 + (tid >> 3)];

  // k-row (bf16 -> f32 LDS)
  if (tid < 256) {
    unsigned short kv = pqkv[(size_t)s * 768 + 256 + tid];
    khl[tid] = __uint_as_float((unsigned)kv << 16);
  }

  // K-split staged load: half1 = cols 0-127, half2 = cols 128-255.
  const f32x4* src = reinterpret_cast<const f32x4*>(trip + (size_t)s * 12288);
  int r0 = tid >> 4, c0 = tid & 15;
  int r1 = (384 + tid) >> 4, c1 = tid & 15;
  f32x4 pa[4], pb[4];
  pa[0] = src[r0 * 64 + c0 * 2];
  pa[1] = src[r0 * 64 + c0 * 2 + 1];
  pa[2] = src[r1 * 64 + c1 * 2];
  pa[3] = src[r1 * 64 + c1 * 2 + 1];
  pb[0] = src[r0 * 64 + 32 + c0 * 2];
  pb[1] = src[r0 * 64 + 32 + c0 * 2 + 1];
  pb[2] = src[r1 * 64 + 32 + c1 * 2];
  pb[3] = src[r1 * 64 + 32 + c1 * 2 + 1];

  {  // write half1 (waits only on pa's loads via in-order vmcnt)
    int off0 = (r0 << 9) + (c0 << 4);
    off0 ^= (r0 & 7) << 4;
    *reinterpret_cast<bf16x8*>(tAc + off0) = cvt8(pa[0], pa[1]);
    int off1 = (r1 << 9) + (c1 << 4);
    off1 ^= (r1 & 7) << 4;
    *reinterpret_cast<bf16x8*>(tAc + off1) = cvt8(pa[2], pa[3]);
  }
  bar_lgkm();  // [1] half1 staged; pb loads still in flight

  // GEMM kt0-3; B-frags from L2 per kt
  const bf16x8* wp = reinterpret_cast<const bf16x8*>(wfragm);
  f32x4 acc[3];
#pragma unroll
  for (int mt = 0; mt < 3; ++mt) acc[mt] = (f32x4){0.f, 0.f, 0.f, 0.f};
#pragma unroll
  for (int kt = 0; kt < 4; ++kt) {
    bf16x8 w = wp[(wave * 8 + kt) * 64 + lane];
#pragma unroll
    for (int mt = 0; mt < 3; ++mt) {
      int row = mt * 16 + (lane & 15);
      int off = (row << 9) + (kt << 6) + ((lane >> 4) << 4);
      off ^= (row & 7) << 4;
      bf16x8 a = *reinterpret_cast<const bf16x8*>(tAc + off);
      acc[mt] = __builtin_amdgcn_mfma_f32_16x16x32_bf16(a, w, acc[mt], 0, 0, 0);
    }
  }
  {  // write half2
    int off0 = (r0 << 9) + ((16 + c0) << 4);
    off0 ^= (r0 & 7) << 4;
    *reinterpret_cast<bf16x8*>(tAc + off0) = cvt8(pb[0], pb[1]);
    int off1 = (r1 << 9) + ((16 + c1) << 4);
    off1 ^= (r1 & 7) << 4;
    *reinterpret_cast<bf16x8*>(tAc + off1) = cvt8(pb[2], pb[3]);
  }
  bar_lgkm();  // [2] half2 staged

#pragma unroll
  for (int kt = 4; kt < 8; ++kt) {
    bf16x8 w = wp[(wave * 8 + kt) * 64 + lane];
#pragma unroll
    for (int mt = 0; mt < 3; ++mt) {
      int row = mt * 16 + (lane & 15);
      int off = (row << 9) + (kt << 6) + ((lane >> 4) << 4);
      off ^= (row & 7) << 4;
      bf16x8 a = *reinterpret_cast<const bf16x8*>(tAc + off);
      acc[mt] = __builtin_amdgcn_mfma_f32_16x16x32_bf16(a, w, acc[mt], 0, 0, 0);
    }
  }
  bar_lgkm();  // [3] tAc reads done; smem becomes sqS

  // epilogue: waves 0-3 -> sqS[j][n] (sq|sk); waves 4-5 -> svT[d][j] (sv)
  {
    int n = wave * 16 + (lane & 15);
    float bias = biasm[n];
    int jb = (lane >> 4) * 4;
    if (wave < 4) {
#pragma unroll
      for (int mt = 0; mt < 3; ++mt) {
#pragma unroll
        for (int rr = 0; rr < 4; ++rr)
          sqS[(mt * 16 + jb + rr) * SQS_LD + n] = acc[mt][rr] + bias;
      }
    } else {
      int d = n - 64;
#pragma unroll
      for (int mt = 0; mt < 3; ++mt) {
#pragma unroll
        for (int rr = 0; rr < 4; ++rr)
          svT[d * SVT_LD + mt * 16 + jb + rr] = acc[mt][rr] + bias;
      }
    }
  }
  bar_lgkm();  // [4] sqS/svT ready

  // scores: thread (j = tid>>3, dq = tid&7); sq/sk read ONCE, 8 h partials,
  // 3-step shfl_xor reduce within the 8-thread dq group.
  {
    int j = tid >> 3, dq = tid & 7;
    f32x4 sq = *reinterpret_cast<const f32x4*>(sqS + j * SQS_LD + dq * 4);
    f32x4 sk = *reinterpret_cast<const f32x4*>(sqS + j * SQS_LD + 32 + dq * 4);
    const unsigned short* qrow = pqkv + (size_t)(rowbase + j) * 768;
    float val[8];
#pragma unroll
    for (int h = 0; h < 8; ++h) {
      uint2 qw = *reinterpret_cast<const uint2*>(qrow + h * 32 + dq * 4);
      f32x4 kh = *reinterpret_cast<const f32x4*>(khl + h * 32 + dq * 4);
      float v = (__uint_as_float(qw.x << 16) + sq.x) * (kh.x + sk.x);
      v += (__uint_as_float(qw.x & 0xFFFF0000u) + sq.y) * (kh.y + sk.y);
      v += (__uint_as_float(qw.y << 16) + sq.z) * (kh.z + sk.z);
      v += (__uint_as_float(qw.y & 0xFFFF0000u) + sq.w) * (kh.w + sk.w);
      val[h] = v;
    }
#pragma unroll
    for (int h = 0; h < 8; ++h) {
      val[h] += __shfl_xor(val[h], 1);
      val[h] += __shfl_xor(val[h], 2);
      val[h] += __shfl_xor(val[h], 4);
    }
    float sc = val[0];
#pragma unroll
    for (int h = 1; h < 8; ++h) sc = (dq == h) ? val[h] : sc;  // static select
    pbuf[dq][j] = sc * 0.17677669529663687f + maskr;
  }
  bar_lgkm();  // [5] scores ready

  // softmax: wave w (<4) handles heads {2w, 2w+1} == the heads its own PV
  // threads read -> no barrier needed between softmax and PV (wave-coherent
  // LDS; lgkmcnt(0) below orders the ds_write -> ds_read within the wave).
  if (wave < 4) {
#pragma unroll
    for (int hh = 0; hh < 2; ++hh) {
      int h = wave * 2 + hh;
      float x = (lane < 48) ? pbuf[h][lane] : -INFINITY;
      float m = x;
#pragma unroll
      for (int off = 32; off; off >>= 1) m = fmaxf(m, __shfl_xor(m, off));
      float e = (lane < 48) ? __expf(x - m) : 0.f;
      float sum = e;
#pragma unroll
      for (int off = 32; off; off >>= 1) sum += __shfl_xor(sum, off);
      if (lane < 48) pbuf[h][lane] = e / sum;
    }
    asm volatile("s_waitcnt lgkmcnt(0)" ::: "memory");

    // PV: thread (h = tid>>5, d = tid&31); v bf16 from pqkv (L2), sv/p LDS
    int h = tid >> 5, d = tid & 31;
    const unsigned short* vbase = pqkv + (size_t)rowbase * 768 + 512 + tid % 256;
    float a = 0.f;
#pragma unroll
    for (int j4 = 0; j4 < 12; ++j4) {
      f32x4 p4 = *reinterpret_cast<const f32x4*>(&pbuf[h][j4 * 4]);
      f32x4 sv4 = *reinterpret_cast<const f32x4*>(svT + d * SVT_LD + j4 * 4);
      float v0 = __uint_as_float((unsigned)vbase[(size_t)(j4 * 4 + 0) * 768] << 16);
      float v1 = __uint_as_float((unsigned)vbase[(size_t)(j4 * 4 + 1) * 768] << 16);
      float v2 = __uint_as_float((unsigned)vbase[(size_t)(j4 * 4 + 2) * 768] << 16);
      float v3 = __uint_as_float((unsigned)vbase[(size_t)(j4 * 4 + 3) * 768] << 16);
      a += p4.x * (v0 + sv4.x);
      a += p4.y * (v1 + sv4.y);
      a += p4.z * (v2 + sv4.z);
      a += p4.w * (v3 + sv4.w);
    }
    out[(size_t)s * 256 + tid] = a;
  }
}

// ---------------------------------------------------------------------------
extern "C" void kernel_launch(void* const* d_in, const int* in_sizes, int n_in,
                              void* d_out, int out_size, void* d_ws, size_t ws_size,
                              hipStream_t stream) {
  const float* mask = (const float*)d_in[0];
  const float* pair = (const float*)d_in[1];
  const float* trip = (const float*)d_in[2];
  const float* Wq = (const float*)d_in[3];
  const float* bq = (const float*)d_in[4];
  const float* Wk = (const float*)d_in[5];
  const float* bk = (const float*)d_in[6];
  const float* Wv = (const float*)d_in[7];
  const float* bv = (const float*)d_in[8];
  const float* Wsq = (const float*)d_in[9];
  const float* bsq = (const float*)d_in[10];
  const float* Wsk = (const float*)d_in[11];
  const float* bsk = (const float*)d_in[12];
  const float* Wsv = (const float*)d_in[13];
  const float* bsv = (const float*)d_in[14];

  char* ws = (char*)d_ws;
  unsigned short* pqkv = (unsigned short*)ws;                    // 7,077,888 B
  unsigned short* wfrag_main = (unsigned short*)(ws + 7077888);  // 49,152 B
  float* biasm = (float*)(ws + 7127040);                         // 384 B

  pair_proj_kernel<<<768, 384, 0, stream>>>(pair, Wq, Wk, Wv, bq, bk, bv,
                                            Wsq, Wsk, Wsv, bsq, bsk, bsv,
                                            pqkv, wfrag_main, biasm);
  e2e_fused<<<4608, 384, 0, stream>>>(mask, trip, pqkv, wfrag_main, biasm,
                                      (float*)d_out);
}